// Round 13
// baseline (342.168 us; speedup 1.0000x reference)
//
#include <hip/hip_runtime.h>
#include <math.h>

typedef _Float16 half8 __attribute__((ext_vector_type(8)));
typedef float f32x4 __attribute__((ext_vector_type(4)));

constexpr int kNFFT    = 1024;
constexpr int kHop     = 320;
constexpr int kMels    = 128;
constexpr int kFrames  = 1000;
constexpr int kBatch   = 32;
constexpr int kXLen    = 320000;
constexpr int kYLen    = kXLen - 1;          // 319999
constexpr int kYOff    = 512;                // center-pad offset
constexpr float kPre   = 0.97f;
constexpr int kPStride = 544;                // power row stride (bins padded 513->544)
// Hann support: basis columns 112..911 nonzero -> k-steps 3..28 only
constexpr int kKsLo    = 3;
constexpr int kKsHi    = 28;                 // inclusive; 26 steps

// ws layout (offsets in _Float16 elements). ypad slots retained but UNUSED
// since r13 (stft reads x directly); frags offset kept stable.
constexpr size_t kFragLvl  = 64ull * 32 * 64 * 8;               // 1,048,576 halfs per level
constexpr size_t kFragOff  = 2ull * kBatch * 328704;            // 21,037,056 (legacy)
constexpr size_t kMelFrOff = kFragOff + 2 * kFragLvl;           // 23,134,208
constexpr size_t kMelFrSz  = 8ull * 17 * 64 * 8;                // 69,632 halfs
constexpr size_t kPowOff   = kMelFrOff + kMelFrSz;              // 23,203,840

// prep grid: frag + mel only (r13: y-stage deleted — fused into stft B-path)
constexpr int kFragBlks   = 131072 / 256;                       // 512
constexpr int kMelBlks    = (8 * 17 * 64) / 256;                // 34
constexpr int kPrepGrid   = kFragBlks + kMelBlks;               // 546

// ---- prep: fourier frags (16x16 layout) / mel frags ----
__global__ void prep_all(const float* __restrict__ x, const float* __restrict__ basis,
                         const float* __restrict__ melb, _Float16* __restrict__ ws) {
    _Float16* fr    = ws + kFragOff;
    _Float16* melfr = ws + kMelFrOff;
    const int bid = blockIdx.x;
    const int tid = threadIdx.x;

    if (bid < kFragBlks) {
        // --- fourier basis -> 16x16x32 A-fragments, 2-level f16 split ---
        // packed rows: 0..512 cos bins 0..512; 513..1023 sin bins 1..511 (orig r+1)
        // frag[lv][g][ks][lane][j]: A[m=16g+(lane&15)][k=32ks+(lane>>4)*8+j]
        int id = bid * 256 + tid;                   // < 131072
        int L  = id & 63;
        int ks = (id >> 6) & 31;
        int g  = id >> 11;                          // 0..63
        int r  = 16 * g + (L & 15);
        int orig = (r <= 512) ? r : r + 1;
        const float* src = basis + (size_t)orig * kNFFT + 32 * ks + (L >> 4) * 8;
        float4 s0 = *(const float4*)(src);
        float4 s1 = *(const float4*)(src + 4);
        float a[8] = {s0.x, s0.y, s0.z, s0.w, s1.x, s1.y, s1.z, s1.w};
        half8 hv, mv;
        #pragma unroll
        for (int j = 0; j < 8; ++j) {
            _Float16 h = (_Float16)a[j];
            hv[j] = h;
            mv[j] = (_Float16)(a[j] - (float)h);
        }
        _Float16* dst = fr + (size_t)id * 8;        // id == (g*32+ks)*64+L
        *(half8*)dst = hv;
        *(half8*)(dst + kFragLvl) = mv;
    } else {
        // --- mel basis -> 16x16x32 A-fragments, f16, K padded 513->544 ---
        int id = (bid - kFragBlks) * 256 + tid;
        if (id >= 8 * 17 * 64) return;
        int f = id / 1088;
        int rem = id - f * 1088;
        int ks = rem >> 6;
        int L = rem & 63;
        int m = 16 * f + (L & 15);
        int kb = 32 * ks + (L >> 4) * 8;
        half8 hv;
        #pragma unroll
        for (int j = 0; j < 8; ++j) {
            int k = kb + j;
            hv[j] = (k < 513) ? (_Float16)melb[(size_t)m * 513 + k] : (_Float16)0.0f;
        }
        *(half8*)(melfr + (size_t)id * 8) = hv;
    }
}

// ---- main: 3-term split-f16 MFMA STFT + power, x-direct B-path ----
// Schedule FROZEN at the round-5 optimum (r0-r12: all schedule levers —
// phases, counted vmcnt, barrier domains, occupancy +/-, 32x32 shape,
// barrier-free, anti-phase stagger — land at 42-48% MfmaUtil; settled).
// ROUND-13 CHANGE: delete prep's y-stage (126MB of pure data movement).
// B-path reads x (f32) directly: pre-emphasis v = x[g+1]-0.97*x[g] and the
// f16 hi/lo split run in-kernel. Numerically identical (same f32 math, same
// accumulation order). Register discipline: raw x (36 VGPR) paid for by
// SINGLE-buffered bh/bm (-32): raw loads issue P1/P2, conversion runs at
// END of P3 after the last mfma2 reading the old bh/bm (WAR-safe).
// vmcnt(0) at P3 (uncounted compiler B-loads; r0/r2: counted==drain here).
// Edge waves (~2/128 positions) take per-lane-masked loads + select, gated
// by a wave-uniform dirty predicate.
// SPILL TRIPWIRE: WRITE_SIZE must stay ~34MB (r1: spill -> GBs, 6x slower).
// power[b][t(1024)][bin(544 pad)] f16.
__global__ __launch_bounds__(256, 2)
void stft_power(const _Float16* __restrict__ frags,
                const float* __restrict__ x,
                _Float16* __restrict__ pw) {
    __shared__ __align__(16) _Float16 ash[2][16 * 512];   // dbuf x 16 frags x 1KB
    const int tid  = threadIdx.x;
    const int w    = tid >> 6;                            // 0..3
    const int lane = tid & 63;
    const int quad = lane >> 4;
    const int l16  = lane & 15;
    const int nt = blockIdx.x, g = blockIdx.y, b = blockIdx.z;
    const int t0 = nt * 256 + w * 64;
    const float* xb = x + (size_t)b * kXLen;

    f32x4 acc[8][4] = {};
    float4 XA[4], XB[4];
    float  XC[4];
    half8  bh[4], bm[4];

    auto dirtyW = [&](int ks) {   // wave-uniform: any lane needs guarding?
        int offmin = t0 * kHop + ks * 32;
        int offmax = (t0 + 63) * kHop + ks * 32 + 24;
        return (offmin < kYOff) || (offmax - kYOff > kXLen - 16);
    };
    auto stageA = [&](int ks, int pbuf) {
        #pragma unroll
        for (int c = 0; c < 4; ++c) {
            int slot = w + 4 * c;                 // 4 waves x 4 slots = 16
            int f = slot & 7, lv = slot >> 3;
            int Gf = (f < 4) ? (4 * g + f) : (32 + 4 * g + (f - 4));
            const _Float16* gp = frags + (size_t)lv * kFragLvl
                               + ((size_t)(Gf * 32 + ks) * 64 + lane) * 8;
            __builtin_amdgcn_global_load_lds(
                (const __attribute__((address_space(1))) void*)gp,
                (__attribute__((address_space(3))) void*)&ash[pbuf][slot * 512],
                16, 0, 0);
        }
    };
    // issue raw x loads for k-step ks, nf pair {nf0, nf0+1}
    auto loadX = [&](int ks, int nf0) {
        bool dirty = dirtyW(ks);
        #pragma unroll
        for (int nf = nf0; nf < nf0 + 2; ++nf) {
            int yi = (t0 + nf * 16 + l16) * kHop + ks * 32 + quad * 8 - kYOff;
            if (!dirty) {
                XA[nf] = *(const float4*)(xb + yi);
                XB[nf] = *(const float4*)(xb + yi + 4);
                XC[nf] = xb[yi + 8];
            } else {
                bool ld8 = (yi >= 0) && (yi <= kXLen - 8);   // x[yi..yi+7] valid
                if (ld8) {
                    XA[nf] = *(const float4*)(xb + yi);
                    XB[nf] = *(const float4*)(xb + yi + 4);
                } else {
                    XA[nf] = float4{0.f, 0.f, 0.f, 0.f};
                    XB[nf] = float4{0.f, 0.f, 0.f, 0.f};
                }
                XC[nf] = (yi >= 0 && yi + 8 < kXLen) ? xb[yi + 8] : 0.f;
            }
        }
    };
    // raw -> pre-emphasis -> f16 hi/lo split (deferred to after loads retire)
    auto convX = [&](int ks) {
        bool dirty = dirtyW(ks);
        #pragma unroll
        for (int nf = 0; nf < 4; ++nf) {
            float xx[9] = {XA[nf].x, XA[nf].y, XA[nf].z, XA[nf].w,
                           XB[nf].x, XB[nf].y, XB[nf].z, XB[nf].w, XC[nf]};
            int yi = (t0 + nf * 16 + l16) * kHop + ks * 32 + quad * 8 - kYOff;
            #pragma unroll
            for (int j = 0; j < 8; ++j) {
                float v = xx[j + 1] - kPre * xx[j];
                if (dirty) v = (yi + j < kYLen) ? v : 0.f;  // yi<0 lanes: zero loads -> v=0 already
                _Float16 h = (_Float16)v;
                bh[nf][j] = h;
                bm[nf][j] = (_Float16)(v - (float)h);
            }
        }
    };
    auto mfma2 = [&](int f0, half8 h0, half8 m0, half8 h1, half8 m1) {
        #pragma unroll
        for (int nf = 0; nf < 4; ++nf) {
            f32x4 a = acc[f0][nf];
            a = __builtin_amdgcn_mfma_f32_16x16x32_f16(h0, bh[nf], a, 0, 0, 0);
            a = __builtin_amdgcn_mfma_f32_16x16x32_f16(m0, bh[nf], a, 0, 0, 0);
            a = __builtin_amdgcn_mfma_f32_16x16x32_f16(h0, bm[nf], a, 0, 0, 0);
            acc[f0][nf] = a;
            f32x4 c = acc[f0 + 1][nf];
            c = __builtin_amdgcn_mfma_f32_16x16x32_f16(h1, bh[nf], c, 0, 0, 0);
            c = __builtin_amdgcn_mfma_f32_16x16x32_f16(m1, bh[nf], c, 0, 0, 0);
            c = __builtin_amdgcn_mfma_f32_16x16x32_f16(h1, bm[nf], c, 0, 0, 0);
            acc[f0 + 1][nf] = c;
        }
    };

    // one K-step: consume bh/bm + buf[pbuf]; prefetch ks+1 frags (P0) and raw
    // x (P1/P2); P3: drain, mfma, then convert raw -> bh/bm (single buffer).
    auto step = [&](int ks, int pbuf, bool next) {
        #pragma unroll
        for (int p = 0; p < 4; ++p) {
            const int f0 = 2 * p;
            half8 h0 = *(const half8*)&ash[pbuf][f0 * 512 + lane * 8];
            half8 m0 = *(const half8*)&ash[pbuf][(8 + f0) * 512 + lane * 8];
            half8 h1 = *(const half8*)&ash[pbuf][(f0 + 1) * 512 + lane * 8];
            half8 m1 = *(const half8*)&ash[pbuf][(9 + f0) * 512 + lane * 8];
            if (p == 0 && next) stageA(ks + 1, pbuf ^ 1);
            if (p == 1 && next) loadX(ks + 1, 0);
            if (p == 2 && next) loadX(ks + 1, 2);
            if (p == 3)
                asm volatile("s_waitcnt vmcnt(0)" ::: "memory");
            __builtin_amdgcn_s_barrier();
            __builtin_amdgcn_s_setprio(1);
            mfma2(f0, h0, m0, h1, m1);
            __builtin_amdgcn_s_setprio(0);
            if (p == 3 && next) convX(ks + 1);   // after last use of old bh/bm
            __builtin_amdgcn_s_barrier();
        }
    };

    // prologue: stage k-step 3 into buf0, load+convert its B, drain once.
    stageA(kKsLo, 0);
    loadX(kKsLo, 0);
    loadX(kKsLo, 2);
    asm volatile("s_waitcnt vmcnt(0)" ::: "memory");
    convX(kKsLo);
    __builtin_amdgcn_s_barrier();

    for (int kss = 0; kss < 13; ++kss) {
        int ks = kKsLo + 2 * kss;
        step(ks,     0, true);
        step(ks + 1, 1, kss < 12);
    }

    // epilogue: power = cos^2 + sin^2; chunk f (cos) pairs with f+4 (sin, same bin)
    #pragma unroll
    for (int mf = 0; mf < 4; ++mf) {
        int b0 = 64 * g + 16 * mf + 4 * quad;
        #pragma unroll
        for (int nf = 0; nf < 4; ++nf) {
            int t = t0 + nf * 16 + l16;
            size_t row = ((size_t)((b << 10) + t)) * kPStride;
            struct alignas(8) h4 { _Float16 v[4]; } pp;
            #pragma unroll
            for (int rr = 0; rr < 4; ++rr) {
                float pA = acc[mf][nf][rr];
                float pB = acc[4 + mf][nf][rr];
                float p2 = pA * pA + pB * pB;
                if (g == 0 && mf == 0 && quad == 0 && rr == 0) {
                    // packed row 0 = cos bin 0 (sin==0); paired row 512 = cos bin 512
                    p2 = pA * pA;
                    pw[row + 512] = (_Float16)(pB * pB);
                }
                pp.v[rr] = (_Float16)p2;
            }
            *(decltype(pp)*)&pw[row + b0] = pp;
        }
    }
}

// ---- mel + log via MFMA, LDS-staged pw tile (r10) ----
__global__ __launch_bounds__(512)
void mel_mfma(const _Float16* __restrict__ melfr, const _Float16* __restrict__ pw,
              float* __restrict__ out) {
    __shared__ __align__(16) _Float16 psh[64 * 576];   // 72KB, row = 72 x 16B chunks
    const int tid  = threadIdx.x;
    const int w    = tid >> 6;           // 0..7
    const int lane = tid & 63;
    const int quad = lane >> 4;
    const int l16  = lane & 15;
    const int tw   = w & 3;              // frame tile within block
    const int mh   = w >> 2;             // mel half (0: mels 0-63, 1: 64-127)
    const int nt = blockIdx.x, b = blockIdx.y;
    const int t0 = nt * 64;

    // stage pw rows t0..t0+63, K=544 (68 chunks of 16B), swizzled chunk index
    for (int c = tid; c < 64 * 68; c += 512) {
        int row = c / 68;
        int col = c - row * 68;
        *(half8*)&psh[row * 576 + ((col ^ (row & 7)) << 3)] =
            *(const half8*)(pw + ((size_t)((b << 10) + t0 + row)) * kPStride + col * 8);
    }
    __syncthreads();

    const int t = t0 + tw * 16 + l16;
    const int lrow = tw * 16 + l16;      // LDS row
    const int rkey = lrow & 7;           // swizzle key
    f32x4 acc[4] = {};
    const _Float16* mfr0 = melfr + ((size_t)(mh * 4) * 17 * 64 + lane) * 8;
    #pragma unroll
    for (int ks = 0; ks < 17; ++ks) {
        half8 bp = *(const half8*)&psh[lrow * 576 + (((4 * ks + quad) ^ rkey) << 3)];
        #pragma unroll
        for (int f = 0; f < 4; ++f) {
            half8 af = *(const half8*)(mfr0 + (size_t)(f * 17 + ks) * 64 * 8);
            acc[f] = __builtin_amdgcn_mfma_f32_16x16x32_f16(af, bp, acc[f], 0, 0, 0);
        }
    }
    if (t < kFrames) {
        #pragma unroll
        for (int f = 0; f < 4; ++f) {
            #pragma unroll
            for (int r = 0; r < 4; ++r) {
                int m = mh * 64 + 16 * f + 4 * quad + r;
                out[((size_t)(b * kMels + m)) * kFrames + t] =
                    (__logf(acc[f][r] + 1e-5f) + 4.5f) * 0.2f;
            }
        }
    }
}

extern "C" void kernel_launch(void* const* d_in, const int* in_sizes, int n_in,
                              void* d_out, int out_size, void* d_ws, size_t ws_size,
                              hipStream_t stream) {
    const float* x     = (const float*)d_in[0];
    const float* basis = (const float*)d_in[1];
    const float* melb  = (const float*)d_in[2];
    float* out = (float*)d_out;

    _Float16* ws    = (_Float16*)d_ws;
    _Float16* frags = ws + kFragOff;
    _Float16* melfr = ws + kMelFrOff;
    _Float16* pw    = ws + kPowOff;

    prep_all<<<dim3(kPrepGrid), 256, 0, stream>>>(x, basis, melb, ws);
    stft_power<<<dim3(4, 8, kBatch), 256, 0, stream>>>(frags, x, pw);
    mel_mfma<<<dim3(16, kBatch), 512, 0, stream>>>(melfr, pw, out);
}

// Round 14
// 239.881 us; speedup vs baseline: 1.4264x; 1.4264x over previous
//
#include <hip/hip_runtime.h>
#include <math.h>

typedef _Float16 half8 __attribute__((ext_vector_type(8)));
typedef float f32x4 __attribute__((ext_vector_type(4)));

constexpr int kNFFT    = 1024;
constexpr int kHop     = 320;
constexpr int kMels    = 128;
constexpr int kFrames  = 1000;
constexpr int kBatch   = 32;
constexpr int kXLen    = 320000;
constexpr int kYLen    = kXLen - 1;          // 319999
constexpr int kYPad    = 328704;             // >= 1023*320+1024, mult of 2048
constexpr int kYOff    = 512;                // center-pad offset
constexpr float kPre   = 0.97f;
constexpr int kPStride = 544;                // power row stride (bins padded 513->544)
// Hann support: basis columns 112..911 nonzero -> k-steps 3..28 only
constexpr int kKsLo    = 3;
constexpr int kKsHi    = 28;                 // inclusive; 26 steps

// ws layout (offsets in _Float16 elements)
constexpr size_t kYLvl     = (size_t)kBatch * kYPad;            // halfs per level
constexpr size_t kFragLvl  = 64ull * 32 * 64 * 8;               // 1,048,576 halfs per level
constexpr size_t kFragOff  = 2 * kYLvl;                         // 21,037,056
constexpr size_t kMelFrOff = kFragOff + 2 * kFragLvl;           // 23,134,208
constexpr size_t kMelFrSz  = 8ull * 17 * 64 * 8;                // 69,632 halfs
constexpr size_t kPowOff   = kMelFrOff + kMelFrSz;              // 23,203,840

// fused prep grid partition (r10-exact: uncoarsened y — r11 coarsening was
// neutral-to-slightly-worse; r13 y-fusion into stft regressed 78%)
constexpr int kYJobBlks   = (kYPad / 8 + 255) / 256;            // 161
constexpr int kYJobTotal  = kYJobBlks * kBatch;                 // 5152
constexpr int kFragBlks   = 131072 / 256;                       // 512
constexpr int kMelBlks    = (8 * 17 * 64) / 256;                // 34
constexpr int kPrepGrid   = kYJobTotal + kFragBlks + kMelBlks;  // 5698

// ---- fused prep: y split / fourier frags (16x16 layout) / mel frags ----
__global__ void prep_all(const float* __restrict__ x, const float* __restrict__ basis,
                         const float* __restrict__ melb, _Float16* __restrict__ ws) {
    _Float16* ypad  = ws;
    _Float16* fr    = ws + kFragOff;
    _Float16* melfr = ws + kMelFrOff;
    const int bid = blockIdx.x;
    const int tid = threadIdx.x;

    if (bid < kYJobTotal) {
        // --- pre-emphasis + center pad, 2-level f16 split, 8 elems/thread ---
        // (3-term scheme REQUIRED: r7's 2-term dropped ah*bm -> absmax 0.469,
        //  30x over threshold. Separate kernel REQUIRED: r13's in-stft fusion
        //  put this VALU work on the barrier-locked critical path, -78%.)
        int b = bid / kYJobBlks;
        int blk = bid - b * kYJobBlks;
        int e0 = (blk * 256 + tid) * 8;
        if (e0 >= kYPad) return;
        const float* xb = x + (size_t)b * kXLen;
        int yi = e0 - kYOff;
        float v[8];
        if (yi >= 0 && yi <= kXLen - 9) {
            float4 A = *(const float4*)(xb + yi);
            float4 B = *(const float4*)(xb + yi + 4);
            float C = xb[yi + 8];
            v[0] = A.y - kPre * A.x;  v[1] = A.z - kPre * A.y;
            v[2] = A.w - kPre * A.z;  v[3] = B.x - kPre * A.w;
            v[4] = B.y - kPre * B.x;  v[5] = B.z - kPre * B.y;
            v[6] = B.w - kPre * B.z;  v[7] = C   - kPre * B.w;
        } else {
            #pragma unroll
            for (int j = 0; j < 8; ++j) {
                int g = yi + j;
                v[j] = (g >= 0 && g < kYLen) ? xb[g + 1] - kPre * xb[g] : 0.0f;
            }
        }
        half8 hv, mv;
        #pragma unroll
        for (int j = 0; j < 8; ++j) {
            _Float16 h = (_Float16)v[j];
            hv[j] = h;
            mv[j] = (_Float16)(v[j] - (float)h);
        }
        size_t idx = (size_t)b * kYPad + e0;
        *(half8*)(ypad + idx) = hv;
        *(half8*)(ypad + idx + kYLvl) = mv;
    } else if (bid < kYJobTotal + kFragBlks) {
        // --- fourier basis -> 16x16x32 A-fragments, 2-level f16 split ---
        // packed rows: 0..512 cos bins 0..512; 513..1023 sin bins 1..511 (orig r+1)
        // frag[lv][g][ks][lane][j]: A[m=16g+(lane&15)][k=32ks+(lane>>4)*8+j]
        int id = (bid - kYJobTotal) * 256 + tid;   // < 131072
        int L  = id & 63;
        int ks = (id >> 6) & 31;
        int g  = id >> 11;                          // 0..63
        int r  = 16 * g + (L & 15);
        int orig = (r <= 512) ? r : r + 1;
        const float* src = basis + (size_t)orig * kNFFT + 32 * ks + (L >> 4) * 8;
        float4 s0 = *(const float4*)(src);
        float4 s1 = *(const float4*)(src + 4);
        float a[8] = {s0.x, s0.y, s0.z, s0.w, s1.x, s1.y, s1.z, s1.w};
        half8 hv, mv;
        #pragma unroll
        for (int j = 0; j < 8; ++j) {
            _Float16 h = (_Float16)a[j];
            hv[j] = h;
            mv[j] = (_Float16)(a[j] - (float)h);
        }
        _Float16* dst = fr + (size_t)id * 8;        // id == (g*32+ks)*64+L
        *(half8*)dst = hv;
        *(half8*)(dst + kFragLvl) = mv;
    } else {
        // --- mel basis -> 16x16x32 A-fragments, f16, K padded 513->544 ---
        int id = (bid - kYJobTotal - kFragBlks) * 256 + tid;
        if (id >= 8 * 17 * 64) return;
        int f = id / 1088;
        int rem = id - f * 1088;
        int ks = rem >> 6;
        int L = rem & 63;
        int m = 16 * f + (L & 15);
        int kb = 32 * ks + (L >> 4) * 8;
        half8 hv;
        #pragma unroll
        for (int j = 0; j < 8; ++j) {
            int k = kb + j;
            hv[j] = (k < 513) ? (_Float16)melb[(size_t)m * 513 + k] : (_Float16)0.0f;
        }
        *(half8*)(melfr + (size_t)id * 8) = hv;
    }
}

// ---- main: 3-term split-f16 MFMA STFT + power, 4-wave blocks ----
// FROZEN at the round-5 empirical optimum (155.5us, MfmaUtil ~47.6%).
// Design space bracketed r0-r13; settled negatives:
//  r1/r9: occupancy levers — (512,4) spills acc; halved tile (nf=2) drops
//         MFMA/phase faster than TLP covers (189us).
//  r4: 32x32x16 dependency-bound (6-deep chains) — 189us.
//  r6: barrier-free direct-global A exposes raw L2 latency — 175us.
//  r7: 2-term precision cut fails absmax by 30x — 3-term load-bearing.
//  r8: 25-step rebase +5us (unpaired-tail bubble).
//  r12: anti-phase stagger null (blocks re-phase-lock or HW_ID parity moot).
//  r13: y-prep fusion puts conv VALU on barrier-locked critical path (-78%).
// Per k-step: 4 sub-phases {4x ds_read_b128 + prefetch slice -> s_barrier ->
// setprio(1) 24 MFMA setprio(0) -> s_barrier}. Counted vmcnt(8) once per
// k-step (P3: 12 outstanding - 4 stage = 8; retires only the stage loads).
// power[b][t(1024)][bin(544 pad)] f16.
__global__ __launch_bounds__(256, 2)
void stft_power(const _Float16* __restrict__ frags,
                const _Float16* __restrict__ ypad,
                _Float16* __restrict__ pw) {
    __shared__ __align__(16) _Float16 ash[2][16 * 512];   // dbuf x 16 frags x 1KB
    const int tid  = threadIdx.x;
    const int w    = tid >> 6;                            // 0..3
    const int lane = tid & 63;
    const int quad = lane >> 4;
    const int l16  = lane & 15;
    const int nt = blockIdx.x, g = blockIdx.y, b = blockIdx.z;
    const int t0 = nt * 256 + w * 64;
    const _Float16* yb0 = ypad + (size_t)b * kYPad;
    const _Float16* yb1 = yb0 + kYLvl;

    f32x4 acc[8][4] = {};

    auto stageA = [&](int ks, int pbuf) {
        #pragma unroll
        for (int c = 0; c < 4; ++c) {
            int slot = w + 4 * c;                 // 4 waves x 4 slots = 16
            int f = slot & 7, lv = slot >> 3;
            int Gf = (f < 4) ? (4 * g + f) : (32 + 4 * g + (f - 4));
            const _Float16* gp = frags + (size_t)lv * kFragLvl
                               + ((size_t)(Gf * 32 + ks) * 64 + lane) * 8;
            __builtin_amdgcn_global_load_lds(
                (const __attribute__((address_space(1))) void*)gp,
                (__attribute__((address_space(3))) void*)&ash[pbuf][slot * 512],
                16, 0, 0);
        }
    };
    auto loadB2 = [&](int ks, int nf0, half8* bh, half8* bm) {
        #pragma unroll
        for (int nf = nf0; nf < nf0 + 2; ++nf) {
            int off = (t0 + nf * 16 + l16) * kHop + ks * 32 + quad * 8;
            bh[nf] = *(const half8*)(yb0 + off);
            bm[nf] = *(const half8*)(yb1 + off);
        }
    };
    auto mfma2 = [&](int f0, half8 h0, half8 m0, half8 h1, half8 m1,
                     half8* bh, half8* bm) {
        #pragma unroll
        for (int nf = 0; nf < 4; ++nf) {
            f32x4 a = acc[f0][nf];
            a = __builtin_amdgcn_mfma_f32_16x16x32_f16(h0, bh[nf], a, 0, 0, 0);
            a = __builtin_amdgcn_mfma_f32_16x16x32_f16(m0, bh[nf], a, 0, 0, 0);
            a = __builtin_amdgcn_mfma_f32_16x16x32_f16(h0, bm[nf], a, 0, 0, 0);
            acc[f0][nf] = a;
            f32x4 c = acc[f0 + 1][nf];
            c = __builtin_amdgcn_mfma_f32_16x16x32_f16(h1, bh[nf], c, 0, 0, 0);
            c = __builtin_amdgcn_mfma_f32_16x16x32_f16(m1, bh[nf], c, 0, 0, 0);
            c = __builtin_amdgcn_mfma_f32_16x16x32_f16(h1, bm[nf], c, 0, 0, 0);
            acc[f0 + 1][nf] = c;
        }
    };

    // one K-step: consume B-regs (bhC/bmC) + buf[pbuf]; prefetch next k-step's
    // frags into buf[pbuf^1] (P0) and B into bhN/bmN (P1/P2). 4 sub-phases.
    auto step = [&](int ks, int pbuf, half8* bhC, half8* bmC,
                    half8* bhN, half8* bmN, bool next) {
        #pragma unroll
        for (int p = 0; p < 4; ++p) {
            const int f0 = 2 * p;
            half8 h0 = *(const half8*)&ash[pbuf][f0 * 512 + lane * 8];
            half8 m0 = *(const half8*)&ash[pbuf][(8 + f0) * 512 + lane * 8];
            half8 h1 = *(const half8*)&ash[pbuf][(f0 + 1) * 512 + lane * 8];
            half8 m1 = *(const half8*)&ash[pbuf][(9 + f0) * 512 + lane * 8];
            if (p == 0 && next) stageA(ks + 1, pbuf ^ 1);
            if (p == 1 && next) loadB2(ks + 1, 0, bhN, bmN);
            if (p == 2 && next) loadB2(ks + 1, 2, bhN, bmN);
            if (p == 3)  // retire the 4 stage loads (oldest; issued at P0), keep 8 B-loads in flight
                asm volatile("s_waitcnt vmcnt(8)" ::: "memory");
            __builtin_amdgcn_s_barrier();
            __builtin_amdgcn_s_setprio(1);
            mfma2(f0, h0, m0, h1, m1, bhC, bmC);
            __builtin_amdgcn_s_setprio(0);
            __builtin_amdgcn_s_barrier();
        }
    };

    half8 bhA[4], bmA[4], bhB[4], bmB[4];
    // prologue: stage k-step 3 into buf0, load its B, full drain once.
    stageA(kKsLo, 0);
    loadB2(kKsLo, 0, bhA, bmA);
    loadB2(kKsLo, 2, bhA, bmA);
    asm volatile("s_waitcnt vmcnt(0)" ::: "memory");
    __builtin_amdgcn_s_barrier();

    for (int kss = 0; kss < 13; ++kss) {
        int ks = kKsLo + 2 * kss;
        step(ks,     0, bhA, bmA, bhB, bmB, true);
        step(ks + 1, 1, bhB, bmB, bhA, bmA, kss < 12);
    }

    // epilogue: power = cos^2 + sin^2; chunk f (cos) pairs with f+4 (sin, same bin)
    #pragma unroll
    for (int mf = 0; mf < 4; ++mf) {
        int b0 = 64 * g + 16 * mf + 4 * quad;
        #pragma unroll
        for (int nf = 0; nf < 4; ++nf) {
            int t = t0 + nf * 16 + l16;
            size_t row = ((size_t)((b << 10) + t)) * kPStride;
            struct alignas(8) h4 { _Float16 v[4]; } pp;
            #pragma unroll
            for (int rr = 0; rr < 4; ++rr) {
                float pA = acc[mf][nf][rr];
                float pB = acc[4 + mf][nf][rr];
                float p2 = pA * pA + pB * pB;
                if (g == 0 && mf == 0 && quad == 0 && rr == 0) {
                    // packed row 0 = cos bin 0 (sin==0); paired row 512 = cos bin 512
                    p2 = pA * pA;
                    pw[row + 512] = (_Float16)(pB * pB);
                }
                pp.v[rr] = (_Float16)p2;
            }
            *(decltype(pp)*)&pw[row + b0] = pp;
        }
    }
}

// ---- mel + log via MFMA, LDS-staged pw tile (r10 best) ----
__global__ __launch_bounds__(512)
void mel_mfma(const _Float16* __restrict__ melfr, const _Float16* __restrict__ pw,
              float* __restrict__ out) {
    __shared__ __align__(16) _Float16 psh[64 * 576];   // 72KB, row = 72 x 16B chunks
    const int tid  = threadIdx.x;
    const int w    = tid >> 6;           // 0..7
    const int lane = tid & 63;
    const int quad = lane >> 4;
    const int l16  = lane & 15;
    const int tw   = w & 3;              // frame tile within block
    const int mh   = w >> 2;             // mel half (0: mels 0-63, 1: 64-127)
    const int nt = blockIdx.x, b = blockIdx.y;
    const int t0 = nt * 64;

    // stage pw rows t0..t0+63, K=544 (68 chunks of 16B), swizzled chunk index
    for (int c = tid; c < 64 * 68; c += 512) {
        int row = c / 68;
        int col = c - row * 68;
        *(half8*)&psh[row * 576 + ((col ^ (row & 7)) << 3)] =
            *(const half8*)(pw + ((size_t)((b << 10) + t0 + row)) * kPStride + col * 8);
    }
    __syncthreads();

    const int t = t0 + tw * 16 + l16;
    const int lrow = tw * 16 + l16;      // LDS row
    const int rkey = lrow & 7;           // swizzle key
    f32x4 acc[4] = {};
    const _Float16* mfr0 = melfr + ((size_t)(mh * 4) * 17 * 64 + lane) * 8;
    #pragma unroll
    for (int ks = 0; ks < 17; ++ks) {
        half8 bp = *(const half8*)&psh[lrow * 576 + (((4 * ks + quad) ^ rkey) << 3)];
        #pragma unroll
        for (int f = 0; f < 4; ++f) {
            half8 af = *(const half8*)(mfr0 + (size_t)(f * 17 + ks) * 64 * 8);
            acc[f] = __builtin_amdgcn_mfma_f32_16x16x32_f16(af, bp, acc[f], 0, 0, 0);
        }
    }
    if (t < kFrames) {
        #pragma unroll
        for (int f = 0; f < 4; ++f) {
            #pragma unroll
            for (int r = 0; r < 4; ++r) {
                int m = mh * 64 + 16 * f + 4 * quad + r;
                out[((size_t)(b * kMels + m)) * kFrames + t] =
                    (__logf(acc[f][r] + 1e-5f) + 4.5f) * 0.2f;
            }
        }
    }
}

extern "C" void kernel_launch(void* const* d_in, const int* in_sizes, int n_in,
                              void* d_out, int out_size, void* d_ws, size_t ws_size,
                              hipStream_t stream) {
    const float* x     = (const float*)d_in[0];
    const float* basis = (const float*)d_in[1];
    const float* melb  = (const float*)d_in[2];
    float* out = (float*)d_out;

    _Float16* ws    = (_Float16*)d_ws;
    _Float16* frags = ws + kFragOff;
    _Float16* melfr = ws + kMelFrOff;
    _Float16* pw    = ws + kPowOff;

    prep_all<<<dim3(kPrepGrid), 256, 0, stream>>>(x, basis, melb, ws);
    stft_power<<<dim3(4, 8, kBatch), 256, 0, stream>>>(frags, ws, pw);
    mel_mfma<<<dim3(16, kBatch), 512, 0, stream>>>(melfr, pw, out);
}